// Round 3
// baseline (7521.632 us; speedup 1.0000x reference)
//
#include <hip/hip_runtime.h>
#include <cstdint>
#include <cstddef>

#define N_NODES 100000
#define N_EDGES 1200000
#define ASIZE 256
#define HSIZE 64
#define NTYPES 4
#define NSTEPS 6
#define NGRAPH 64

static __device__ __forceinline__ float sigmoidf_(float x) { return 1.0f / (1.0f + expf(-x)); }

// dot of per-lane register array x[64] with wave-uniform weight row w[64].
// x indices are compile-time after unroll -> stays in VGPRs; w -> s_load_dwordx4.
static __device__ __forceinline__ float dot64(const float* __restrict__ x,
                                              const float* __restrict__ w) {
    const float4* wp = (const float4*)w;
    float t0 = 0.f, t1 = 0.f, t2 = 0.f, t3 = 0.f;
#pragma unroll
    for (int k4 = 0; k4 < 16; ++k4) {
        float4 ww = wp[k4];
        t0 = fmaf(x[4 * k4 + 0], ww.x, t0);
        t1 = fmaf(x[4 * k4 + 1], ww.y, t1);
        t2 = fmaf(x[4 * k4 + 2], ww.z, t2);
        t3 = fmaf(x[4 * k4 + 3], ww.w, t3);
    }
    return (t0 + t1) + (t2 + t3);
}

// ---------------- CSR build (by dst) ----------------
__global__ void k_count(const int* __restrict__ dst, int* __restrict__ deg) {
    int e = blockIdx.x * 256 + threadIdx.x;
    if (e < N_EDGES) atomicAdd(&deg[dst[e]], 1);
}

__global__ void k_scan1(const int* __restrict__ deg, int* __restrict__ rs, int* __restrict__ part) {
    __shared__ int sh[256];
    int t = threadIdx.x;
    int base = blockIdx.x * 1024 + t * 4;
    int v0 = (base + 0 < N_NODES) ? deg[base + 0] : 0;
    int v1 = (base + 1 < N_NODES) ? deg[base + 1] : 0;
    int v2 = (base + 2 < N_NODES) ? deg[base + 2] : 0;
    int v3 = (base + 3 < N_NODES) ? deg[base + 3] : 0;
    int s = v0 + v1 + v2 + v3;
    sh[t] = s;
    __syncthreads();
    for (int off = 1; off < 256; off <<= 1) {
        int x = (t >= off) ? sh[t - off] : 0;
        __syncthreads();
        sh[t] += x;
        __syncthreads();
    }
    int excl = sh[t] - s;
    if (t == 255) part[blockIdx.x] = sh[255];
    if (base + 0 < N_NODES) rs[base + 0] = excl;
    if (base + 1 < N_NODES) rs[base + 1] = excl + v0;
    if (base + 2 < N_NODES) rs[base + 2] = excl + v0 + v1;
    if (base + 3 < N_NODES) rs[base + 3] = excl + v0 + v1 + v2;
}

__global__ void k_scan2(int* __restrict__ part, int* __restrict__ rs, int nb) {
    if (threadIdx.x == 0 && blockIdx.x == 0) {
        int run = 0;
        for (int i = 0; i < nb; ++i) { int v = part[i]; part[i] = run; run += v; }
        rs[N_NODES] = run;
    }
}

__global__ void k_scan3(int* __restrict__ rs, const int* __restrict__ part) {
    int i = blockIdx.x * 256 + threadIdx.x;
    if (i < N_NODES) rs[i] += part[i >> 10];
}

__global__ void k_fill(const int* __restrict__ src, const int* __restrict__ dst,
                       const int* __restrict__ ety, const int* __restrict__ rs,
                       int* __restrict__ cur, int* __restrict__ colidx) {
    int e = blockIdx.x * 256 + threadIdx.x;
    if (e < N_EDGES) {
        int d = dst[e];
        int pos = rs[d] + atomicAdd(&cur[d], 1);
        colidx[pos] = ety[e] * N_NODES + src[e];
    }
}

// ---------------- weight prep: rWT[j][k] = rW[k][j]; eWT[t][j][k] = eW[t][k][j] ----------------
__global__ void k_prep(const float* __restrict__ rW, const float* __restrict__ eW,
                       float* __restrict__ rWT, float* __restrict__ eWT) {
    int i = blockIdx.x * 256 + threadIdx.x;
    if (i < 64 * 256) {
        int j = i >> 8, k = i & 255;
        rWT[i] = rW[k * 64 + j];
    }
    if (i < NTYPES * 64 * 64) {
        int t = i >> 12, j = (i >> 6) & 63, k = i & 63;
        eWT[i] = eW[((t << 6) + k) * 64 + j];
    }
}

// ---------------- reduce layer: h0 = ann @ rW + rb ; h = h0  (lane = node) ----------------
__global__ __launch_bounds__(64) void k_reduce(const float* __restrict__ ann,
                                               const float* __restrict__ rWT,
                                               const float* __restrict__ rb,
                                               float* __restrict__ h0, float* __restrict__ h) {
    __shared__ float sacc[64 * 68];   // per-lane private acc row, pad 68 (b128-aligned)
    int l = threadIdx.x;
    int n = blockIdx.x * 64 + l;
    if (n >= N_NODES) return;
    float4* acc = (float4*)(sacc + l * 68);
    const float4* rb4 = (const float4*)rb;
#pragma unroll
    for (int jq = 0; jq < 16; ++jq) acc[jq] = rb4[jq];

    for (int c = 0; c < 4; ++c) {
        float a[64];
        const float4* ap = (const float4*)(ann + (size_t)n * ASIZE + c * 64);
#pragma unroll
        for (int i = 0; i < 16; ++i) {
            float4 v = ap[i];
            a[4 * i + 0] = v.x; a[4 * i + 1] = v.y; a[4 * i + 2] = v.z; a[4 * i + 3] = v.w;
        }
        for (int jq = 0; jq < 16; ++jq) {
            float4 s = acc[jq];
            s.x += dot64(a, rWT + (jq * 4 + 0) * 256 + c * 64);
            s.y += dot64(a, rWT + (jq * 4 + 1) * 256 + c * 64);
            s.z += dot64(a, rWT + (jq * 4 + 2) * 256 + c * 64);
            s.w += dot64(a, rWT + (jq * 4 + 3) * 256 + c * 64);
            acc[jq] = s;
        }
    }
    float4* o0 = (float4*)(h0 + (size_t)n * 64);
    float4* o1 = (float4*)(h + (size_t)n * 64);
#pragma unroll
    for (int jq = 0; jq < 16; ++jq) { float4 s = acc[jq]; o0[jq] = s; o1[jq] = s; }
}

// ---------------- per-edge-type transform (lane = node, h row read once for all 4 types) ----
__global__ __launch_bounds__(256) void k_transform(const float* __restrict__ h,
                                                   const float* __restrict__ eWT,
                                                   const float* __restrict__ eb,
                                                   float* __restrict__ trans) {
    int n = blockIdx.x * 256 + threadIdx.x;
    if (n >= N_NODES) return;
    float hr[64];
    const float4* hp = (const float4*)(h + (size_t)n * 64);
#pragma unroll
    for (int i = 0; i < 16; ++i) {
        float4 v = hp[i];
        hr[4 * i + 0] = v.x; hr[4 * i + 1] = v.y; hr[4 * i + 2] = v.z; hr[4 * i + 3] = v.w;
    }
    for (int t = 0; t < 4; ++t) {
        float4* op = (float4*)(trans + ((size_t)t * N_NODES + n) * 64);
        const float* wt = eWT + t * 64 * 64;
        const float* bt = eb + t * 64;
        for (int jq = 0; jq < 16; ++jq) {
            float4 o;
            o.x = dot64(hr, wt + (jq * 4 + 0) * 64) + bt[jq * 4 + 0];
            o.y = dot64(hr, wt + (jq * 4 + 1) * 64) + bt[jq * 4 + 1];
            o.z = dot64(hr, wt + (jq * 4 + 2) * 64) + bt[jq * 4 + 2];
            o.w = dot64(hr, wt + (jq * 4 + 3) * 64) + bt[jq * 4 + 3];
            op[jq] = o;
        }
    }
}

// ---------------- edge aggregate: a[n] = sum of incoming trans rows (lane = col) ----------------
__global__ void k_aggregate(const float* __restrict__ trans, const int* __restrict__ rs,
                            const int* __restrict__ colidx, float* __restrict__ a) {
    int l = threadIdx.x & 63;
    int n = blockIdx.x * 4 + (threadIdx.x >> 6);
    int beg = rs[n], end = rs[n + 1];
    float acc0 = 0.f, acc1 = 0.f;
    int s = beg;
    for (; s + 1 < end; s += 2) {
        int c0 = colidx[s], c1 = colidx[s + 1];
        acc0 += trans[(size_t)c0 * 64 + l];
        acc1 += trans[(size_t)c1 * 64 + l];
    }
    if (s < end) acc0 += trans[(size_t)colidx[s] * 64 + l];
    a[(size_t)n * 64 + l] = acc0 + acc1;
}

// ---------------- fused GRU cell (lane = node, one pass, no persisted gate vectors) ----------
__global__ __launch_bounds__(64) void k_gru(const float* __restrict__ A, float* __restrict__ H,
                                            const float* __restrict__ Wi,
                                            const float* __restrict__ Wh,
                                            const float* __restrict__ Bi,
                                            const float* __restrict__ Bh) {
    int n = blockIdx.x * 64 + threadIdx.x;
    if (n >= N_NODES) return;
    float a[64], hv[64];
    const float4* ap = (const float4*)(A + (size_t)n * 64);
    float4* Hp = (float4*)(H + (size_t)n * 64);
#pragma unroll
    for (int i = 0; i < 16; ++i) {
        float4 v = ap[i];
        a[4 * i + 0] = v.x; a[4 * i + 1] = v.y; a[4 * i + 2] = v.z; a[4 * i + 3] = v.w;
        float4 w = Hp[i];
        hv[4 * i + 0] = w.x; hv[4 * i + 1] = w.y; hv[4 * i + 2] = w.z; hv[4 * i + 3] = w.w;
    }
    for (int jq = 0; jq < 16; ++jq) {
        float4 hold = Hp[jq];   // L1-hot reload; gives h_j for runtime j
        float out[4];
#pragma unroll
        for (int u = 0; u < 4; ++u) {
            int j = jq * 4 + u;
            float iR = dot64(a, Wi + (size_t)j * 64);
            float hR = dot64(hv, Wh + (size_t)j * 64);
            float iZ = dot64(a, Wi + (size_t)(64 + j) * 64);
            float hZ = dot64(hv, Wh + (size_t)(64 + j) * 64);
            float iN = dot64(a, Wi + (size_t)(128 + j) * 64);
            float hN = dot64(hv, Wh + (size_t)(128 + j) * 64);
            float r = sigmoidf_(iR + Bi[j] + hR + Bh[j]);
            float z = sigmoidf_(iZ + Bi[64 + j] + hZ + Bh[64 + j]);
            float nn = tanhf(iN + Bi[128 + j] + r * (hN + Bh[128 + j]));
            float hj = (u == 0) ? hold.x : (u == 1) ? hold.y : (u == 2) ? hold.z : hold.w;
            out[u] = (1.0f - z) * nn + z * hj;
        }
        float4 o; o.x = out[0]; o.y = out[1]; o.z = out[2]; o.w = out[3];
        Hp[jq] = o;
    }
}

// ---------------- pooling: segmented, atomic-free (gid sorted) ----------------
__global__ void k_bounds(const int* __restrict__ gid, int* __restrict__ start) {
    int n = blockIdx.x * 256 + threadIdx.x;
    if (n < N_NODES) {
        int g = gid[n];
        if (n == 0) {
            for (int x = 0; x <= g; ++x) start[x] = 0;
        } else {
            int pg = gid[n - 1];
            for (int x = pg + 1; x <= g; ++x) start[x] = n;
        }
        if (n == N_NODES - 1) {
            for (int x = g + 1; x <= NGRAPH; ++x) start[x] = N_NODES;
        }
    }
}

__global__ void k_gate2(const float* __restrict__ H, const float* __restrict__ H0,
                        const float* __restrict__ gW, const float* __restrict__ gb,
                        float* __restrict__ gate) {
    int l = threadIdx.x & 63;
    int n = blockIdx.x * 4 + (threadIdx.x >> 6);
    float v = H[(size_t)n * 64 + l] * gW[l] + H0[(size_t)n * 64 + l] * gW[64 + l];
    for (int off = 32; off > 0; off >>= 1) v += __shfl_xor(v, off, 64);
    if (l == 0) gate[n] = v + gb[0];
}

__global__ __launch_bounds__(256) void k_pool(const float* __restrict__ H,
                                              const float* __restrict__ H0,
                                              const float* __restrict__ gate,
                                              const int* __restrict__ start,
                                              float* __restrict__ ro) {
    int g = blockIdx.x;
    int beg = start[g], end = start[g + 1];
    int t = threadIdx.x;
    int lane = t & 63, wave = t >> 6;
    __shared__ float sred[256];
    __shared__ float shh[4][64], sh0[4][64];

    float m = -INFINITY;
    for (int n = beg + t; n < end; n += 256) m = fmaxf(m, gate[n]);
    sred[t] = m; __syncthreads();
    for (int off = 128; off > 0; off >>= 1) {
        if (t < off) sred[t] = fmaxf(sred[t], sred[t + off]);
        __syncthreads();
    }
    m = sred[0];
    if (!isfinite(m)) m = 0.0f;
    __syncthreads();

    float s = 0.f;
    for (int n = beg + t; n < end; n += 256) s += expf(gate[n] - m);
    sred[t] = s; __syncthreads();
    for (int off = 128; off > 0; off >>= 1) {
        if (t < off) sred[t] += sred[t + off];
        __syncthreads();
    }
    float inv_denom = 1.0f / sred[0];
    __syncthreads();

    float ah = 0.f, ah0 = 0.f;
    for (int n = beg + wave; n < end; n += 4) {
        float alpha = expf(gate[n] - m) * inv_denom;
        ah  += alpha * H [(size_t)n * 64 + lane];
        ah0 += alpha * H0[(size_t)n * 64 + lane];
    }
    shh[wave][lane] = ah; sh0[wave][lane] = ah0;
    __syncthreads();
    if (wave == 0) {
        float r  = shh[0][lane] + shh[1][lane] + shh[2][lane] + shh[3][lane];
        float r0 = sh0[0][lane] + sh0[1][lane] + sh0[2][lane] + sh0[3][lane];
        ro[g * 128 + lane]      = r;
        ro[g * 128 + 64 + lane] = r0;
    }
}

__global__ void k_logits(const float* __restrict__ ro, const float* __restrict__ oW,
                         const float* __restrict__ ob, float* __restrict__ out) {
    int t = threadIdx.x;
    int b = t >> 1;
    int c = t & 1;
    float acc = ob[c];
    for (int k = 0; k < 128; ++k) acc = fmaf(ro[b * 128 + k], oW[k * 2 + c], acc);
    out[b * 2 + c] = acc;
}

extern "C" void kernel_launch(void* const* d_in, const int* in_sizes, int n_in,
                              void* d_out, int out_size, void* d_ws, size_t ws_size,
                              hipStream_t stream) {
    (void)in_sizes; (void)n_in; (void)out_size; (void)ws_size;
    const float* ann = (const float*)d_in[0];
    const int* src   = (const int*)d_in[1];
    const int* dst   = (const int*)d_in[2];
    const int* ety   = (const int*)d_in[3];
    const int* gid   = (const int*)d_in[4];
    const float* rW  = (const float*)d_in[5];
    const float* rb  = (const float*)d_in[6];
    const float* eW  = (const float*)d_in[7];
    const float* eb  = (const float*)d_in[8];
    const float* Wi  = (const float*)d_in[9];
    const float* Bi  = (const float*)d_in[10];
    const float* Wh  = (const float*)d_in[11];
    const float* Bh  = (const float*)d_in[12];
    const float* gW  = (const float*)d_in[13];
    const float* gb  = (const float*)d_in[14];
    const float* oW  = (const float*)d_in[15];
    const float* ob  = (const float*)d_in[16];
    float* out = (float*)d_out;

    char* p = (char*)d_ws;
    auto take = [&](size_t nbytes) -> void* {
        void* r = (void*)p;
        p += (nbytes + 255) & ~((size_t)255);
        return r;
    };
    float* h0    = (float*)take((size_t)N_NODES * 64 * 4);
    float* h     = (float*)take((size_t)N_NODES * 64 * 4);
    float* abuf  = (float*)take((size_t)N_NODES * 64 * 4);
    float* trans = (float*)take((size_t)NTYPES * N_NODES * 64 * 4);
    float* rWT   = (float*)take(64 * 256 * 4);
    float* eWT   = (float*)take(NTYPES * 64 * 64 * 4);
    int* deg     = (int*)take((size_t)N_NODES * 4);
    int* cur     = (int*)take((size_t)N_NODES * 4);
    int* rs      = (int*)take((size_t)(N_NODES + 1) * 4);
    int* part    = (int*)take(512);
    int* colidx  = (int*)take((size_t)N_EDGES * 4);
    float* gate  = (float*)take((size_t)N_NODES * 4);
    int* start   = (int*)take((size_t)(NGRAPH + 1) * 4);
    float* ro    = (float*)take(NGRAPH * 128 * 4);

    // ---- CSR build
    hipMemsetAsync(deg, 0, (size_t)N_NODES * 4, stream);
    hipMemsetAsync(cur, 0, (size_t)N_NODES * 4, stream);
    k_count<<<(N_EDGES + 255) / 256, 256, 0, stream>>>(dst, deg);
    int nb = (N_NODES + 1023) / 1024;
    k_scan1<<<nb, 256, 0, stream>>>(deg, rs, part);
    k_scan2<<<1, 64, 0, stream>>>(part, rs, nb);
    k_scan3<<<(N_NODES + 255) / 256, 256, 0, stream>>>(rs, part);
    k_fill<<<(N_EDGES + 255) / 256, 256, 0, stream>>>(src, dst, ety, rs, cur, colidx);

    // ---- weight prep + graph bounds
    k_prep<<<64, 256, 0, stream>>>(rW, eW, rWT, eWT);
    k_bounds<<<(N_NODES + 255) / 256, 256, 0, stream>>>(gid, start);

    // ---- reduce layer
    k_reduce<<<(N_NODES + 63) / 64, 64, 0, stream>>>(ann, rWT, rb, h0, h);

    // ---- message-passing steps
    for (int s = 0; s < NSTEPS; ++s) {
        k_transform<<<(N_NODES + 255) / 256, 256, 0, stream>>>(h, eWT, eb, trans);
        k_aggregate<<<N_NODES / 4, 256, 0, stream>>>(trans, rs, colidx, abuf);
        k_gru<<<(N_NODES + 63) / 64, 64, 0, stream>>>(abuf, h, Wi, Wh, Bi, Bh);
    }

    // ---- pooling + classifier (atomic-free)
    k_gate2<<<N_NODES / 4, 256, 0, stream>>>(h, h0, gW, gb, gate);
    k_pool<<<NGRAPH, 256, 0, stream>>>(h, h0, gate, start, ro);
    k_logits<<<1, 128, 0, stream>>>(ro, oW, ob, out);
}

// Round 4
// 1771.060 us; speedup vs baseline: 4.2470x; 4.2470x over previous
//
#include <hip/hip_runtime.h>
#include <cstdint>
#include <cstddef>

#define N_NODES 100000
#define N_EDGES 1200000
#define ASIZE 256
#define HSIZE 64
#define NTYPES 4
#define NSTEPS 6
#define NGRAPH 64

static __device__ __forceinline__ float sigmoidf_(float x) { return 1.0f / (1.0f + expf(-x)); }

// ---------------- CSR build (by dst) ----------------
__global__ void k_count(const int* __restrict__ dst, int* __restrict__ deg) {
    int e = blockIdx.x * 256 + threadIdx.x;
    if (e < N_EDGES) atomicAdd(&deg[dst[e]], 1);
}

__global__ void k_scan1(const int* __restrict__ deg, int* __restrict__ rs, int* __restrict__ part) {
    __shared__ int sh[256];
    int t = threadIdx.x;
    int base = blockIdx.x * 1024 + t * 4;
    int v0 = (base + 0 < N_NODES) ? deg[base + 0] : 0;
    int v1 = (base + 1 < N_NODES) ? deg[base + 1] : 0;
    int v2 = (base + 2 < N_NODES) ? deg[base + 2] : 0;
    int v3 = (base + 3 < N_NODES) ? deg[base + 3] : 0;
    int s = v0 + v1 + v2 + v3;
    sh[t] = s;
    __syncthreads();
    for (int off = 1; off < 256; off <<= 1) {
        int x = (t >= off) ? sh[t - off] : 0;
        __syncthreads();
        sh[t] += x;
        __syncthreads();
    }
    int excl = sh[t] - s;
    if (t == 255) part[blockIdx.x] = sh[255];
    if (base + 0 < N_NODES) rs[base + 0] = excl;
    if (base + 1 < N_NODES) rs[base + 1] = excl + v0;
    if (base + 2 < N_NODES) rs[base + 2] = excl + v0 + v1;
    if (base + 3 < N_NODES) rs[base + 3] = excl + v0 + v1 + v2;
}

__global__ void k_scan2(int* __restrict__ part, int* __restrict__ rs, int nb) {
    if (threadIdx.x == 0 && blockIdx.x == 0) {
        int run = 0;
        for (int i = 0; i < nb; ++i) { int v = part[i]; part[i] = run; run += v; }
        rs[N_NODES] = run;
    }
}

__global__ void k_scan3(int* __restrict__ rs, const int* __restrict__ part) {
    int i = blockIdx.x * 256 + threadIdx.x;
    if (i < N_NODES) rs[i] += part[i >> 10];
}

// colidx holds a precomputed float-offset into buf1: src*448 + 192 + ety*64
__global__ void k_fill(const int* __restrict__ src, const int* __restrict__ dst,
                       const int* __restrict__ ety, const int* __restrict__ rs,
                       int* __restrict__ cur, int* __restrict__ colidx) {
    int e = blockIdx.x * 256 + threadIdx.x;
    if (e < N_EDGES) {
        int d = dst[e];
        int pos = rs[d] + atomicAdd(&cur[d], 1);
        colidx[pos] = src[e] * 448 + 192 + ety[e] * 64;
    }
}

// ---------------- weight prep ----------------
// W448[k][m]: m<192 -> Wh[(g*64+j)][k] with m=j*3+g (gate-interleaved gh cols)
//             m>=192 -> eW[t][k][jj] with m=192+t*64+jj (trans cols)
// bias448: m<192 -> Bh[g*64+j]; else eb[t*64+jj]
// WiA[k][j*3+g] = Wi[(g*64+j)][k]; biA[j*3+g] = Bi[g*64+j]
__global__ void k_prep2(const float* __restrict__ Wh, const float* __restrict__ Bh,
                        const float* __restrict__ eW, const float* __restrict__ eb,
                        const float* __restrict__ Wi, const float* __restrict__ Bi,
                        float* __restrict__ W448, float* __restrict__ bias448,
                        float* __restrict__ WiA, float* __restrict__ biA) {
    int idx = blockIdx.x * 256 + threadIdx.x;
    if (idx < 64 * 448) {
        int k = idx / 448, m = idx % 448;
        float v;
        if (m < 192) {
            int j = m / 3, g = m % 3;
            v = Wh[(g * 64 + j) * 64 + k];
        } else {
            v = eW[(size_t)(m - 192 >> 6) * 4096 + k * 64 + ((m - 192) & 63)];
        }
        W448[idx] = v;
    }
    if (idx < 64 * 192) {
        int k = idx / 192, m = idx % 192;
        int j = m / 3, g = m % 3;
        WiA[idx] = Wi[(g * 64 + j) * 64 + k];
    }
    if (idx < 448) {
        bias448[idx] = (idx < 192) ? Bh[(idx % 3) * 64 + idx / 3] : eb[idx - 192];
    }
    if (idx < 192) {
        biA[idx] = Bi[(idx % 3) * 64 + idx / 3];
    }
}

// ---------------- generic tiled GEMM: Y[N][M] = X[N][K] @ W[K][M] + bias ----------------
// block: 256 thr; tile 128 nodes x 64 cols (mtile = blockIdx.x*64); thread micro 8x4.
__global__ __launch_bounds__(256) void k_gemm(const float* __restrict__ X, int ldx, int K,
                                              const float* __restrict__ W, int ldw,
                                              const float* __restrict__ bias,
                                              float* __restrict__ Y, float* __restrict__ Y2,
                                              int M) {
    __shared__ float sX[128 * 66];
    __shared__ float sW[64 * 64];
    int tid = threadIdx.x;
    int mtile = blockIdx.x * 64;
    int ntile = blockIdx.y * 128;
    int tc4 = (tid & 15) * 4;
    int tr = tid >> 4;
    float4 acc[8];
#pragma unroll
    for (int i = 0; i < 8; ++i) acc[i] = make_float4(0.f, 0.f, 0.f, 0.f);

    int nkc = K >> 6;
    for (int kc = 0; kc < nkc; ++kc) {
        if (kc) __syncthreads();
        // stage X tile [128 nodes][64 k] -> sX stride 66
#pragma unroll
        for (int i = 0; i < 8; ++i) {
            int lin4 = (i * 256 + tid) * 4;
            int nl = lin4 >> 6, kk = lin4 & 63;
            int n = ntile + nl;
            float4 v = make_float4(0.f, 0.f, 0.f, 0.f);
            if (n < N_NODES) v = *(const float4*)(X + (size_t)n * ldx + kc * 64 + kk);
            float* d = sX + nl * 66 + kk;
            d[0] = v.x; d[1] = v.y; d[2] = v.z; d[3] = v.w;
        }
        // stage W tile [64 k][64 m]
#pragma unroll
        for (int i = 0; i < 4; ++i) {
            int lin4 = (i * 256 + tid) * 4;
            int kk = lin4 >> 6, c = lin4 & 63;
            float4 v = *(const float4*)(W + (size_t)(kc * 64 + kk) * ldw + mtile + c);
            *(float4*)(sW + kk * 64 + c) = v;
        }
        __syncthreads();
        const float* xr = sX + tr * 8 * 66;
        const float* wr = sW + tc4;
        for (int kk = 0; kk < 64; kk += 2) {
            float4 wA = *(const float4*)(wr + kk * 64);
            float4 wB = *(const float4*)(wr + (kk + 1) * 64);
            float xA[8], xB[8];
#pragma unroll
            for (int i = 0; i < 8; ++i) { xA[i] = xr[i * 66 + kk]; xB[i] = xr[i * 66 + kk + 1]; }
#pragma unroll
            for (int i = 0; i < 8; ++i) {
                acc[i].x = fmaf(xA[i], wA.x, acc[i].x);
                acc[i].y = fmaf(xA[i], wA.y, acc[i].y);
                acc[i].z = fmaf(xA[i], wA.z, acc[i].z);
                acc[i].w = fmaf(xA[i], wA.w, acc[i].w);
            }
#pragma unroll
            for (int i = 0; i < 8; ++i) {
                acc[i].x = fmaf(xB[i], wB.x, acc[i].x);
                acc[i].y = fmaf(xB[i], wB.y, acc[i].y);
                acc[i].z = fmaf(xB[i], wB.z, acc[i].z);
                acc[i].w = fmaf(xB[i], wB.w, acc[i].w);
            }
        }
    }
    float4 bv = *(const float4*)(bias + mtile + tc4);
#pragma unroll
    for (int i = 0; i < 8; ++i) {
        int n = ntile + tr * 8 + i;
        if (n < N_NODES) {
            float4 y;
            y.x = acc[i].x + bv.x; y.y = acc[i].y + bv.y;
            y.z = acc[i].z + bv.z; y.w = acc[i].w + bv.w;
            *(float4*)(Y + (size_t)n * M + mtile + tc4) = y;
            if (Y2) *(float4*)(Y2 + (size_t)n * M + mtile + tc4) = y;
        }
    }
}

// ---------------- edge aggregate: a[n] = sum of incoming trans rows from buf1 ----------------
__global__ void k_aggregate(const float* __restrict__ buf1, const int* __restrict__ rs,
                            const int* __restrict__ colidx, float* __restrict__ a) {
    int l = threadIdx.x & 63;
    int n = blockIdx.x * 4 + (threadIdx.x >> 6);
    int beg = rs[n], end = rs[n + 1];
    float acc0 = 0.f, acc1 = 0.f;
    int s = beg;
    for (; s + 1 < end; s += 2) {
        int c0 = colidx[s], c1 = colidx[s + 1];
        acc0 += buf1[(size_t)c0 + l];
        acc1 += buf1[(size_t)c1 + l];
    }
    if (s < end) acc0 += buf1[(size_t)colidx[s] + l];
    a[(size_t)n * 64 + l] = acc0 + acc1;
}

// ---------------- fused gi-GEMM + GRU gate epilogue ----------------
// tile: 64 nodes x 192 cols (cols arranged j*3+g); thread: 4 nodes x 12 cols.
// gh (bias included) read from buf1 cols 0..191 (same j*3+g arrangement). H updated in place.
__global__ __launch_bounds__(256) void k_gruF(const float* __restrict__ A,
                                              const float* __restrict__ WiA,
                                              const float* __restrict__ biA,
                                              const float* __restrict__ buf1,
                                              float* __restrict__ H) {
    __shared__ float sX[64 * 34];
    __shared__ float sW[32 * 192];
    int tid = threadIdx.x;
    int ntile = blockIdx.x * 64;
    int tc = tid & 15;
    int tr = tid >> 4;
    float acc[4][12];
#pragma unroll
    for (int i = 0; i < 4; ++i)
#pragma unroll
        for (int c = 0; c < 12; ++c) acc[i][c] = 0.f;

    for (int kc = 0; kc < 2; ++kc) {
        if (kc) __syncthreads();
        // stage X (a) tile [64 nodes][32 k] stride 34
#pragma unroll
        for (int i = 0; i < 2; ++i) {
            int lin4 = (i * 256 + tid) * 4;
            int nl = lin4 >> 5, kk = lin4 & 31;
            int n = ntile + nl;
            float4 v = make_float4(0.f, 0.f, 0.f, 0.f);
            if (n < N_NODES) v = *(const float4*)(A + (size_t)n * 64 + kc * 32 + kk);
            float* d = sX + nl * 34 + kk;
            d[0] = v.x; d[1] = v.y; d[2] = v.z; d[3] = v.w;
        }
        // stage W chunk [32 k][192 m]: thread -> row tid>>3, cols (tid&7)*24..+23
        {
            int kk = tid >> 3, c = (tid & 7) * 24;
            const float* srcp = WiA + (size_t)(kc * 32 + kk) * 192 + c;
            float* d = sW + kk * 192 + c;
#pragma unroll
            for (int u = 0; u < 6; ++u) *(float4*)(d + 4 * u) = *(const float4*)(srcp + 4 * u);
        }
        __syncthreads();
        const float* xr = sX + tr * 4 * 34;
        const float* wr = sW + tc * 12;
        for (int kk = 0; kk < 32; kk += 2) {
            float4 w0 = *(const float4*)(wr + kk * 192);
            float4 w1 = *(const float4*)(wr + kk * 192 + 4);
            float4 w2 = *(const float4*)(wr + kk * 192 + 8);
            float4 u0 = *(const float4*)(wr + (kk + 1) * 192);
            float4 u1 = *(const float4*)(wr + (kk + 1) * 192 + 4);
            float4 u2 = *(const float4*)(wr + (kk + 1) * 192 + 8);
            float xA[4], xB[4];
#pragma unroll
            for (int i = 0; i < 4; ++i) { xA[i] = xr[i * 34 + kk]; xB[i] = xr[i * 34 + kk + 1]; }
#pragma unroll
            for (int i = 0; i < 4; ++i) {
                acc[i][0]  = fmaf(xA[i], w0.x, acc[i][0]);
                acc[i][1]  = fmaf(xA[i], w0.y, acc[i][1]);
                acc[i][2]  = fmaf(xA[i], w0.z, acc[i][2]);
                acc[i][3]  = fmaf(xA[i], w0.w, acc[i][3]);
                acc[i][4]  = fmaf(xA[i], w1.x, acc[i][4]);
                acc[i][5]  = fmaf(xA[i], w1.y, acc[i][5]);
                acc[i][6]  = fmaf(xA[i], w1.z, acc[i][6]);
                acc[i][7]  = fmaf(xA[i], w1.w, acc[i][7]);
                acc[i][8]  = fmaf(xA[i], w2.x, acc[i][8]);
                acc[i][9]  = fmaf(xA[i], w2.y, acc[i][9]);
                acc[i][10] = fmaf(xA[i], w2.z, acc[i][10]);
                acc[i][11] = fmaf(xA[i], w2.w, acc[i][11]);
            }
#pragma unroll
            for (int i = 0; i < 4; ++i) {
                acc[i][0]  = fmaf(xB[i], u0.x, acc[i][0]);
                acc[i][1]  = fmaf(xB[i], u0.y, acc[i][1]);
                acc[i][2]  = fmaf(xB[i], u0.z, acc[i][2]);
                acc[i][3]  = fmaf(xB[i], u0.w, acc[i][3]);
                acc[i][4]  = fmaf(xB[i], u1.x, acc[i][4]);
                acc[i][5]  = fmaf(xB[i], u1.y, acc[i][5]);
                acc[i][6]  = fmaf(xB[i], u1.z, acc[i][6]);
                acc[i][7]  = fmaf(xB[i], u1.w, acc[i][7]);
                acc[i][8]  = fmaf(xB[i], u2.x, acc[i][8]);
                acc[i][9]  = fmaf(xB[i], u2.y, acc[i][9]);
                acc[i][10] = fmaf(xB[i], u2.z, acc[i][10]);
                acc[i][11] = fmaf(xB[i], u2.w, acc[i][11]);
            }
        }
    }
    // epilogue: GRU gate math
    float bb[12];
    {
        float4 b0 = *(const float4*)(biA + tc * 12);
        float4 b1 = *(const float4*)(biA + tc * 12 + 4);
        float4 b2 = *(const float4*)(biA + tc * 12 + 8);
        bb[0] = b0.x; bb[1] = b0.y; bb[2] = b0.z; bb[3] = b0.w;
        bb[4] = b1.x; bb[5] = b1.y; bb[6] = b1.z; bb[7] = b1.w;
        bb[8] = b2.x; bb[9] = b2.y; bb[10] = b2.z; bb[11] = b2.w;
    }
#pragma unroll
    for (int i = 0; i < 4; ++i) {
        int n = ntile + tr * 4 + i;
        if (n >= N_NODES) continue;
        const float* ghp = buf1 + (size_t)n * 448 + tc * 12;
        float gg[12];
        float4 g0 = *(const float4*)(ghp);
        float4 g1 = *(const float4*)(ghp + 4);
        float4 g2 = *(const float4*)(ghp + 8);
        gg[0] = g0.x; gg[1] = g0.y; gg[2] = g0.z; gg[3] = g0.w;
        gg[4] = g1.x; gg[5] = g1.y; gg[6] = g1.z; gg[7] = g1.w;
        gg[8] = g2.x; gg[9] = g2.y; gg[10] = g2.z; gg[11] = g2.w;
        float4 hv = *(const float4*)(H + (size_t)n * 64 + tc * 4);
        float res[4];
#pragma unroll
        for (int jj = 0; jj < 4; ++jj) {
            int c = jj * 3;
            float r = sigmoidf_(acc[i][c] + bb[c] + gg[c]);
            float z = sigmoidf_(acc[i][c + 1] + bb[c + 1] + gg[c + 1]);
            float nn = tanhf(acc[i][c + 2] + bb[c + 2] + r * gg[c + 2]);
            float hj = (jj == 0) ? hv.x : (jj == 1) ? hv.y : (jj == 2) ? hv.z : hv.w;
            res[jj] = (1.f - z) * nn + z * hj;
        }
        float4 o; o.x = res[0]; o.y = res[1]; o.z = res[2]; o.w = res[3];
        *(float4*)(H + (size_t)n * 64 + tc * 4) = o;
    }
}

// ---------------- pooling: segmented, atomic-free (gid sorted) ----------------
__global__ void k_bounds(const int* __restrict__ gid, int* __restrict__ start) {
    int n = blockIdx.x * 256 + threadIdx.x;
    if (n < N_NODES) {
        int g = gid[n];
        if (n == 0) {
            for (int x = 0; x <= g; ++x) start[x] = 0;
        } else {
            int pg = gid[n - 1];
            for (int x = pg + 1; x <= g; ++x) start[x] = n;
        }
        if (n == N_NODES - 1) {
            for (int x = g + 1; x <= NGRAPH; ++x) start[x] = N_NODES;
        }
    }
}

__global__ void k_gate2(const float* __restrict__ H, const float* __restrict__ H0,
                        const float* __restrict__ gW, const float* __restrict__ gb,
                        float* __restrict__ gate) {
    int l = threadIdx.x & 63;
    int n = blockIdx.x * 4 + (threadIdx.x >> 6);
    float v = H[(size_t)n * 64 + l] * gW[l] + H0[(size_t)n * 64 + l] * gW[64 + l];
    for (int off = 32; off > 0; off >>= 1) v += __shfl_xor(v, off, 64);
    if (l == 0) gate[n] = v + gb[0];
}

__global__ __launch_bounds__(256) void k_pool(const float* __restrict__ H,
                                              const float* __restrict__ H0,
                                              const float* __restrict__ gate,
                                              const int* __restrict__ start,
                                              float* __restrict__ ro) {
    int g = blockIdx.x;
    int beg = start[g], end = start[g + 1];
    int t = threadIdx.x;
    int lane = t & 63, wave = t >> 6;
    __shared__ float sred[256];
    __shared__ float shh[4][64], sh0[4][64];

    float m = -INFINITY;
    for (int n = beg + t; n < end; n += 256) m = fmaxf(m, gate[n]);
    sred[t] = m; __syncthreads();
    for (int off = 128; off > 0; off >>= 1) {
        if (t < off) sred[t] = fmaxf(sred[t], sred[t + off]);
        __syncthreads();
    }
    m = sred[0];
    if (!isfinite(m)) m = 0.0f;
    __syncthreads();

    float s = 0.f;
    for (int n = beg + t; n < end; n += 256) s += expf(gate[n] - m);
    sred[t] = s; __syncthreads();
    for (int off = 128; off > 0; off >>= 1) {
        if (t < off) sred[t] += sred[t + off];
        __syncthreads();
    }
    float inv_denom = 1.0f / sred[0];
    __syncthreads();

    float ah = 0.f, ah0 = 0.f;
    for (int n = beg + wave; n < end; n += 4) {
        float alpha = expf(gate[n] - m) * inv_denom;
        ah  += alpha * H [(size_t)n * 64 + lane];
        ah0 += alpha * H0[(size_t)n * 64 + lane];
    }
    shh[wave][lane] = ah; sh0[wave][lane] = ah0;
    __syncthreads();
    if (wave == 0) {
        float r  = shh[0][lane] + shh[1][lane] + shh[2][lane] + shh[3][lane];
        float r0 = sh0[0][lane] + sh0[1][lane] + sh0[2][lane] + sh0[3][lane];
        ro[g * 128 + lane]      = r;
        ro[g * 128 + 64 + lane] = r0;
    }
}

__global__ void k_logits(const float* __restrict__ ro, const float* __restrict__ oW,
                         const float* __restrict__ ob, float* __restrict__ out) {
    int t = threadIdx.x;
    int b = t >> 1;
    int c = t & 1;
    float acc = ob[c];
    for (int k = 0; k < 128; ++k) acc = fmaf(ro[b * 128 + k], oW[k * 2 + c], acc);
    out[b * 2 + c] = acc;
}

extern "C" void kernel_launch(void* const* d_in, const int* in_sizes, int n_in,
                              void* d_out, int out_size, void* d_ws, size_t ws_size,
                              hipStream_t stream) {
    (void)in_sizes; (void)n_in; (void)out_size; (void)ws_size;
    const float* ann = (const float*)d_in[0];
    const int* src   = (const int*)d_in[1];
    const int* dst   = (const int*)d_in[2];
    const int* ety   = (const int*)d_in[3];
    const int* gid   = (const int*)d_in[4];
    const float* rW  = (const float*)d_in[5];
    const float* rb  = (const float*)d_in[6];
    const float* eW  = (const float*)d_in[7];
    const float* eb  = (const float*)d_in[8];
    const float* Wi  = (const float*)d_in[9];
    const float* Bi  = (const float*)d_in[10];
    const float* Wh  = (const float*)d_in[11];
    const float* Bh  = (const float*)d_in[12];
    const float* gW  = (const float*)d_in[13];
    const float* gb  = (const float*)d_in[14];
    const float* oW  = (const float*)d_in[15];
    const float* ob  = (const float*)d_in[16];
    float* out = (float*)d_out;

    char* p = (char*)d_ws;
    auto take = [&](size_t nbytes) -> void* {
        void* r = (void*)p;
        p += (nbytes + 255) & ~((size_t)255);
        return r;
    };
    float* h0      = (float*)take((size_t)N_NODES * 64 * 4);
    float* h       = (float*)take((size_t)N_NODES * 64 * 4);
    float* abuf    = (float*)take((size_t)N_NODES * 64 * 4);
    float* buf1    = (float*)take((size_t)N_NODES * 448 * 4);   // [gh(192, j*3+g) | trans(4x64)]
    float* W448    = (float*)take(64 * 448 * 4);
    float* bias448 = (float*)take(448 * 4);
    float* WiA     = (float*)take(64 * 192 * 4);
    float* biA     = (float*)take(192 * 4);
    int* deg       = (int*)take((size_t)N_NODES * 4);
    int* cur       = (int*)take((size_t)N_NODES * 4);
    int* rs        = (int*)take((size_t)(N_NODES + 1) * 4);
    int* part      = (int*)take(512);
    int* colidx    = (int*)take((size_t)N_EDGES * 4);
    float* gate    = (float*)take((size_t)N_NODES * 4);
    int* start     = (int*)take((size_t)(NGRAPH + 1) * 4);
    float* ro      = (float*)take(NGRAPH * 128 * 4);

    // ---- CSR build
    hipMemsetAsync(deg, 0, (size_t)N_NODES * 4, stream);
    hipMemsetAsync(cur, 0, (size_t)N_NODES * 4, stream);
    k_count<<<(N_EDGES + 255) / 256, 256, 0, stream>>>(dst, deg);
    int nb = (N_NODES + 1023) / 1024;
    k_scan1<<<nb, 256, 0, stream>>>(deg, rs, part);
    k_scan2<<<1, 64, 0, stream>>>(part, rs, nb);
    k_scan3<<<(N_NODES + 255) / 256, 256, 0, stream>>>(rs, part);
    k_fill<<<(N_EDGES + 255) / 256, 256, 0, stream>>>(src, dst, ety, rs, cur, colidx);

    // ---- weight prep + graph bounds
    k_prep2<<<112, 256, 0, stream>>>(Wh, Bh, eW, eb, Wi, Bi, W448, bias448, WiA, biA);
    k_bounds<<<(N_NODES + 255) / 256, 256, 0, stream>>>(gid, start);

    int ntiles = (N_NODES + 127) / 128;  // 782

    // ---- reduce layer: h = h0 = ann @ rW + rb  (rW already [K=256][M=64])
    k_gemm<<<dim3(1, ntiles), 256, 0, stream>>>(ann, ASIZE, ASIZE, rW, 64, rb, h, h0, 64);

    // ---- message-passing steps
    for (int s = 0; s < NSTEPS; ++s) {
        // [gh | trans] = h @ W448 + bias448
        k_gemm<<<dim3(7, ntiles), 256, 0, stream>>>(h, 64, 64, W448, 448, bias448,
                                                    buf1, nullptr, 448);
        k_aggregate<<<N_NODES / 4, 256, 0, stream>>>(buf1, rs, colidx, abuf);
        k_gruF<<<(N_NODES + 63) / 64, 256, 0, stream>>>(abuf, WiA, biA, buf1, h);
    }

    // ---- pooling + classifier (atomic-free)
    k_gate2<<<N_NODES / 4, 256, 0, stream>>>(h, h0, gW, gb, gate);
    k_pool<<<NGRAPH, 256, 0, stream>>>(h, h0, gate, start, ro);
    k_logits<<<1, 128, 0, stream>>>(ro, oW, ob, out);
}